// Round 4
// baseline (173.496 us; speedup 1.0000x reference)
//
#include <hip/hip_runtime.h>
#include <hip/hip_bf16.h>
#include <math.h>

// GNO collapsed: h = lift(x); per layer h = gelu(h@weff + beff),
//   weff = Wb + c0*(A@T' + qk su^T),  beff = bb + c0*(kq.T' + qbk su),
//   A = Wq@Wk^T, qk = Wq@bk, kq = Wk@bq, qbk = bq.bk     (G-INDEPENDENT)
//   T' = G@Wv + s bv^T,  su = Wv^T s + N bv,  G = h^T h, s = h^T 1,
//   c0 = (1/sqrt(64))/4096.
// Round 16: staging + E off the critical path, conflict-free E.
//  - Wq/Wk staged via global_load_lds DMA (fp32) / VGPR prefetch (bf16)
//    issued BEFORE the G-partial compute; drains at the existing barrier.
//  - Wk diagonally transposed in LDS (conflict-free both sides) so the
//    shadow A=Wq@Wk^T runs as an NN product: kills round-15's 3.4M 8-way
//    bank conflicts (R-side rows at stride-68 were bank-stride-16).
//  - Weight buffers unpadded [64][64] (needed for linear DMA; col-float4
//    reads at stride 64 are 2-way = free).
//  - E before the aflag poll (fills flag-propagation window); Wv/Wb
//    prefetch after E (hidden under combine+cflag).
//  - Sync fabric unchanged (2 polls/layer, packed symmetric partials,
//    wave-linear stc2, all-block chunk combine -- proven 220->103->92 us).

#define NLAYER 4
#define NB 2
#define NN 4096
#define DD 64
#define RPB 32              // rows per block (8192 rows / 256 blocks)
#define NT 256
#define NBLK 256
#define SHP 68              // padded stride for sH/B3 only
#define C0F (1.0f/32768.0f)
#define PSZ 2304            // packed partial floats: 2176 tri + 64 s + 64 pad
#define NCH 128             // combine chunks per batch
#define CHW 18              // floats per combine chunk

typedef __hip_bfloat16 bf16;
typedef unsigned long long u64t;

// ---- LDS float offsets ----
#define O_SH   0            // sH [32][68]  = 2176
#define O_B3   2176         // B3 [64][68]  = 4352  (PS/RED alias; G; weff)
#define O_W1   6528         // [64][64] Wq -> Wv
#define O_W2   10624        // [64][64] A
#define O_W4   14720        // [64][64] Wk -> Wb
#define O_W5   18816        // [64][64] WkT -> T'
#define O_SS   22912
#define O_SU   22976
#define O_BK   23040
#define O_BQ   23104
#define O_BV   23168
#define O_BE   23232
#define O_QK   23296
#define O_KQ   23360
#define O_QBK  23424
#define O_RED  23488        // red [4][64]
#define SM_TOT 23744        // 94976 B -> 1 block/CU

__device__ __forceinline__ float b2f(const bf16 v) { return __bfloat162float(v); }
__device__ __forceinline__ float bfu(unsigned s) {      // bf16 bits -> f32
    return __uint_as_float(s << 16);
}

template <typename T> struct Acc;
template <> struct Acc<float> {
    static __device__ __forceinline__ float ld(const void* p, int i) { return ((const float*)p)[i]; }
    static __device__ __forceinline__ void st(void* p, int i, float v) { ((float*)p)[i] = v; }
};
template <> struct Acc<bf16> {
    static __device__ __forceinline__ float ld(const void* p, int i) { return b2f(((const bf16*)p)[i]); }
    static __device__ __forceinline__ void st(void* p, int i, float v) { ((bf16*)p)[i] = __float2bfloat16(v); }
};

__device__ __forceinline__ float gelu_exact(float x) {
    return 0.5f * x * (1.0f + erff(x * 0.70710678118654752f));
}

// async global->LDS DMA, 16B per lane (fp32 staging; zero VGPR cost)
__device__ __forceinline__ void dma16(const float* g, float* l) {
    __builtin_amdgcn_global_load_lds(
        (const __attribute__((address_space(1))) unsigned int*)g,
        (__attribute__((address_space(3))) unsigned int*)l, 16, 0, 0);
}

// ---- device-coherent helpers (agent scope, relaxed) ----
__device__ __forceinline__ float2 ldc2(const float* p) {
    u64t v = __hip_atomic_load((const u64t*)p, __ATOMIC_RELAXED, __HIP_MEMORY_SCOPE_AGENT);
    float2 r;
    r.x = __uint_as_float((unsigned)v);
    r.y = __uint_as_float((unsigned)(v >> 32));
    return r;
}
__device__ __forceinline__ void stc2(float* p, float a, float b) {
    u64t v = ((u64t)__float_as_uint(b) << 32) | (u64t)__float_as_uint(a);
    __hip_atomic_store((u64t*)p, v, __ATOMIC_RELAXED, __HIP_MEMORY_SCOPE_AGENT);
}
__device__ __forceinline__ unsigned ldw(unsigned* p) {
    return __hip_atomic_load(p, __ATOMIC_RELAXED, __HIP_MEMORY_SCOPE_AGENT);
}
__device__ __forceinline__ void stw(unsigned* p, unsigned v) {
    __hip_atomic_store(p, v, __ATOMIC_RELAXED, __HIP_MEMORY_SCOPE_AGENT);
}
__device__ __forceinline__ void pollw(unsigned* p, unsigned ep) {
    int guard = 0;
    while (ldw(p) < ep && ++guard < (1 << 18)) __builtin_amdgcn_s_sleep(2);
}

// acc[a][b] += sum_k L[a].k * R[k].b
__device__ __forceinline__ void mm4x4(float (&acc)[4][4],
    float4 L0, float4 L1, float4 L2, float4 L3,
    float4 R0, float4 R1, float4 R2, float4 R3)
{
    const float L[4][4] = {{L0.x,L0.y,L0.z,L0.w},{L1.x,L1.y,L1.z,L1.w},
                           {L2.x,L2.y,L2.z,L2.w},{L3.x,L3.y,L3.z,L3.w}};
    const float R[4][4] = {{R0.x,R0.y,R0.z,R0.w},{R1.x,R1.y,R1.z,R1.w},
                           {R2.x,R2.y,R2.z,R2.w},{R3.x,R3.y,R3.z,R3.w}};
    #pragma unroll
    for (int a = 0; a < 4; a++)
        #pragma unroll
        for (int k = 0; k < 4; k++)
            #pragma unroll
            for (int b = 0; b < 4; b++)
                acc[a][b] += L[a][k] * R[k][b];
}

// acc[a][b] += A.a * B.b
__device__ __forceinline__ void outer4x4(float (&acc)[4][4], float4 A, float4 B)
{
    const float Aa[4] = {A.x, A.y, A.z, A.w};
    const float Ba[4] = {B.x, B.y, B.z, B.w};
    #pragma unroll
    for (int a = 0; a < 4; a++)
        #pragma unroll
        for (int b = 0; b < 4; b++)
            acc[a][b] += Aa[a] * Ba[b];
}

template <typename T>
__device__ void run_net(
    const void* x, const void* lw, const void* lb,
    const void* blkw, const void* blkb,
    const void* qw, const void* qb, const void* kw, const void* kb,
    const void* vw, const void* vb, const void* pw, const void* pb,
    void* out, float* Gpart, float* Gg,
    unsigned* aflag, unsigned* cflag,
    float* smem, int blk, int t)
{
    float (*sH)[SHP] = (float(*)[SHP])(smem + O_SH);
    float (*B3)[SHP] = (float(*)[SHP])(smem + O_B3);
    float (*W1)[DD]  = (float(*)[DD])(smem + O_W1);
    float (*W2)[DD]  = (float(*)[DD])(smem + O_W2);
    float (*W4)[DD]  = (float(*)[DD])(smem + O_W4);
    float (*W5)[DD]  = (float(*)[DD])(smem + O_W5);
    float* W1f = smem + O_W1;
    float* W4f = smem + O_W4;
    float* PS  = smem + O_B3;           // packed-partial scratch (aliases B3)
    float* RED = smem + O_B3;           // combine reduction [16][20]
    float* sS  = smem + O_SS;
    float* suS = smem + O_SU;
    float* bkS = smem + O_BK;
    float* bqS = smem + O_BQ;
    float* bvS = smem + O_BV;
    float* beS = smem + O_BE;
    float* qkS = smem + O_QK;
    float* kqS = smem + O_KQ;
    float* qbkS = smem + O_QBK;
    float (*red)[DD] = (float(*)[DD])(smem + O_RED);

    const int row0 = blk * RPB;
    const int bb = blk >> 7;                      // batch of this block
    const int r = t >> 4, c4 = (t & 15) << 2;     // apply/lift mapping
    const int i4 = t >> 4, j4 = t & 15;           // 4x4 tile grid coords
    const int r0 = i4 << 2, c0 = j4 << 2;
    const int Ltr = t & 63, gtr = t >> 6;         // transpose mapping

    // ---- lift: 32 rows of h into resident LDS ----
    #pragma unroll
    for (int a = 0; a < 2; a++) {
        const int row = r + 16 * a, gr = row0 + row;
        float x0 = Acc<T>::ld(x, gr * 3 + 0);
        float x1 = Acc<T>::ld(x, gr * 3 + 1);
        float x2 = Acc<T>::ld(x, gr * 3 + 2);
        float o[4];
        #pragma unroll
        for (int b = 0; b < 4; b++) {
            int c = c4 + b;
            o[b] = Acc<T>::ld(lb, c) + x0 * Acc<T>::ld(lw, c)
                 + x1 * Acc<T>::ld(lw, DD + c) + x2 * Acc<T>::ld(lw, 2 * DD + c);
        }
        *(float4*)&sH[row][c4] = make_float4(o[0], o[1], o[2], o[3]);
    }
    __syncthreads();

    unsigned pq[8], pk[8];              // bf16 VGPR prefetch buffers

    for (int layer = 0; layer < NLAYER; layer++) {
        const unsigned ep = (unsigned)(layer + 1);
        float* GgL = Gg + (size_t)(layer * NB + bb) * PSZ;
        const int wOff = layer * DD * DD, bOff = layer * DD;

        // ---- prefetch Wq/Wk (off-path: overlaps partial compute) ----
        if constexpr (sizeof(T) == 4) {
            const float* qwf = (const float*)qw + wOff;
            const float* kwf = (const float*)kw + wOff;
            #pragma unroll
            for (int k = 0; k < 4; k++) {
                dma16(qwf + 4 * (k * NT + t), &W1f[4 * (k * NT + t)]);
                dma16(kwf + 4 * (k * NT + t), &W4f[4 * (k * NT + t)]);
            }
        } else {
            const unsigned* q32 = (const unsigned*)qw + (wOff >> 1);
            const unsigned* k32 = (const unsigned*)kw + (wOff >> 1);
            #pragma unroll
            for (int k = 0; k < 8; k++) {
                pq[k] = q32[t + k * NT];
                pk[k] = k32[t + k * NT];
            }
        }

        // ---- A: packed symmetric G-partial (upper triangle) into PS ----
        {
            if (i4 <= j4) {
                float m[4][4];
                #pragma unroll
                for (int a = 0; a < 4; a++)
                    #pragma unroll
                    for (int b = 0; b < 4; b++) m[a][b] = 0.f;
                #pragma unroll 8
                for (int n = 0; n < RPB; n++)
                    outer4x4(m, *(const float4*)&sH[n][r0], *(const float4*)&sH[n][c0]);
                float* dst = PS + (i4 * (33 - i4) / 2 + (j4 - i4)) * 16;
                #pragma unroll
                for (int a = 0; a < 4; a++)
                    #pragma unroll
                    for (int b = 0; b < 4; b++) dst[a * 4 + b] = m[a][b];
            }
            if (t < DD) {
                float ss = 0.f;
                #pragma unroll 8
                for (int n = 0; n < RPB; n++) ss += sH[n][t];
                PS[2176 + t] = ss;
                PS[2240 + t] = 0.f;     // pad (combine reduces it blindly)
            }
        }
        __syncthreads();
        // ---- B: wave-linear coherent copy PS -> own Gpart slot ----
        {
            float* slot = Gpart + (size_t)blk * PSZ;
            #pragma unroll
            for (int k2 = 0; k2 < 4; k2++) {
                const int idx = 2 * (t + k2 * NT);
                stc2(&slot[idx], PS[idx], PS[idx + 1]);
            }
            if (t < 128) {
                const int idx = 2 * (t + 4 * NT);
                stc2(&slot[idx], PS[idx], PS[idx + 1]);
            }
        }
        __syncthreads();            // stc2 drained AND Wq/Wk DMA drained
        if (t == 0) stw(&aflag[blk], ep);

        // ---- stage biases; bf16: convert prefetched Wq/Wk into LDS ----
        if (t < DD) {
            bkS[t] = Acc<T>::ld(kb, bOff + t);
            bqS[t] = Acc<T>::ld(qb, bOff + t);
            bvS[t] = Acc<T>::ld(vb, bOff + t);
        }
        if constexpr (sizeof(T) != 4) {
            #pragma unroll
            for (int k = 0; k < 8; k++) {
                const int i2 = t + k * NT;
                unsigned uq = pq[k], uk = pk[k];
                *(float2*)&W1f[2 * i2] = make_float2(bfu(uq & 0xffffu), bfu(uq >> 16));
                *(float2*)&W4f[2 * i2] = make_float2(bfu(uk & 0xffffu), bfu(uk >> 16));
            }
        }
        __syncthreads();            // W1 (Wq), W4 (Wk), biases ready

        // ---- diagonal transpose Wk -> W5 (conflict-free both sides) ----
        #pragma unroll
        for (int k = 0; k < 16; k++) {
            const int i = (Ltr + gtr + 4 * k) & 63;
            W5[i][Ltr] = W4[Ltr][i];
        }
        __syncthreads();            // W5 = Wk^T

        // ---- E (pre-poll shadow): A = Wq@WkT (NN), qk, kq, qbk ----
        {
            float acc[4][4];
            #pragma unroll
            for (int a = 0; a < 4; a++)
                #pragma unroll
                for (int b = 0; b < 4; b++) acc[a][b] = 0.f;
            #pragma unroll 2
            for (int e = 0; e < DD; e += 4)
                mm4x4(acc,
                      *(const float4*)&W1[r0 + 0][e], *(const float4*)&W1[r0 + 1][e],
                      *(const float4*)&W1[r0 + 2][e], *(const float4*)&W1[r0 + 3][e],
                      *(const float4*)&W5[e + 0][c0], *(const float4*)&W5[e + 1][c0],
                      *(const float4*)&W5[e + 2][c0], *(const float4*)&W5[e + 3][c0]);
            #pragma unroll
            for (int a = 0; a < 4; a++)
                *(float4*)&W2[r0 + a][c0] = make_float4(acc[a][0], acc[a][1], acc[a][2], acc[a][3]);

            if (t < DD) {               // qk = Wq@bk
                float u = 0.f;
                for (int e = 0; e < DD; e++) u += W1[t][e] * bkS[e];
                qkS[t] = u;
            } else if (t < 2 * DD) {    // kq = Wk@bq
                const int rr = t - DD;
                float u = 0.f;
                for (int e = 0; e < DD; e++) u += W4[rr][e] * bqS[e];
                kqS[rr] = u;
            } else if (t == 2 * DD) {   // qbk = bq.bk
                float u = 0.f;
                for (int e = 0; e < DD; e++) u += bqS[e] * bkS[e];
                qbkS[0] = u;
            }
        }
        __syncthreads();            // A done; W1/W4 free

        // ---- prefetch Wv/Wb (hidden under combine + cflag window) ----
        if constexpr (sizeof(T) == 4) {
            const float* vwf = (const float*)vw + wOff;
            const float* bwf = (const float*)blkw + wOff;
            #pragma unroll
            for (int k = 0; k < 4; k++) {
                dma16(vwf + 4 * (k * NT + t), &W1f[4 * (k * NT + t)]);
                dma16(bwf + 4 * (k * NT + t), &W4f[4 * (k * NT + t)]);
            }
        } else {
            const unsigned* v32 = (const unsigned*)vw + (wOff >> 1);
            const unsigned* b32 = (const unsigned*)blkw + (wOff >> 1);
            #pragma unroll
            for (int k = 0; k < 8; k++) {
                pq[k] = v32[t + k * NT];
                pk[k] = b32[t + k * NT];
            }
        }

        // ---- D: wait partials; combine own chunk across 128 slots ----
        {
            if (t < NCH) pollw(&aflag[bb * NCH + t], ep);
            __syncthreads();
            const int chunk = blk & (NCH - 1);
            if (t < 144) {
                const int g = t / 9, p2 = t % 9;    // 16 slot-groups x 9 pairs
                const float* base = Gpart + (size_t)(bb * NCH + g * 8) * PSZ
                                  + chunk * CHW + 2 * p2;
                float ax = 0.f, ay = 0.f;
                #pragma unroll
                for (int s2 = 0; s2 < 8; s2++) {
                    float2 v = ldc2(base + (size_t)s2 * PSZ);
                    ax += v.x; ay += v.y;
                }
                RED[g * 20 + 2 * p2]     = ax;
                RED[g * 20 + 2 * p2 + 1] = ay;
            }
            __syncthreads();
            if (t < 9) {
                float s0 = 0.f, s1 = 0.f;
                #pragma unroll
                for (int g = 0; g < 16; g++) {
                    s0 += RED[g * 20 + 2 * t];
                    s1 += RED[g * 20 + 2 * t + 1];
                }
                stc2(&GgL[chunk * CHW + 2 * t], s0, s1);
            }
            __syncthreads();            // Gg stores drained
            if (t == 0) stw(&cflag[blk], ep);
        }

        // ---- bf16: convert prefetched Wv/Wb while cflag propagates ----
        if constexpr (sizeof(T) != 4) {
            #pragma unroll
            for (int k = 0; k < 8; k++) {
                const int i2 = t + k * NT;
                unsigned uv = pq[k], ub = pk[k];
                *(float2*)&W1f[2 * i2] = make_float2(bfu(uv & 0xffffu), bfu(uv >> 16));
                *(float2*)&W4f[2 * i2] = make_float2(bfu(ub & 0xffffu), bfu(ub >> 16));
            }
        }

        // ---- F: wait all 128 chunks; stage G -> B3 (mirrored) ----
        {
            if (t < NCH) pollw(&cflag[bb * NCH + t], ep);
            __syncthreads();            // G visible; W1/W4 staging drained
            if (i4 <= j4) {
                const float* src = GgL + (i4 * (33 - i4) / 2 + (j4 - i4)) * 16;
                #pragma unroll
                for (int a = 0; a < 4; a++)
                    *(float4*)&B3[r0 + a][c0] = *(const float4*)&src[a * 4];
            } else {
                const float* src = GgL + (j4 * (33 - j4) / 2 + (i4 - j4)) * 16;
                #pragma unroll
                for (int a = 0; a < 4; a++)
                    #pragma unroll
                    for (int b = 0; b < 4; b++)
                        B3[r0 + a][c0 + b] = src[b * 4 + a];
            }
            if (t < DD) sS[t] = GgL[2176 + t];
            __syncthreads();
        }

        // ---- G: W5 = T' = G@Wv + s bv^T ; red = su partials ----
        {
            float acc[4][4];
            #pragma unroll
            for (int a = 0; a < 4; a++)
                #pragma unroll
                for (int b = 0; b < 4; b++) acc[a][b] = sS[r0 + a] * bvS[c0 + b];
            #pragma unroll 2
            for (int e = 0; e < DD; e += 4)
                mm4x4(acc,
                      *(const float4*)&B3[r0 + 0][e], *(const float4*)&B3[r0 + 1][e],
                      *(const float4*)&B3[r0 + 2][e], *(const float4*)&B3[r0 + 3][e],
                      *(const float4*)&W1[e + 0][c0], *(const float4*)&W1[e + 1][c0],
                      *(const float4*)&W1[e + 2][c0], *(const float4*)&W1[e + 3][c0]);
            #pragma unroll
            for (int a = 0; a < 4; a++)
                *(float4*)&W5[r0 + a][c0] = make_float4(acc[a][0], acc[a][1], acc[a][2], acc[a][3]);
        }
        {   // su[c] = sum_d s[d]*Wv[d][c] partials
            const int c = t & 63, q = t >> 6;
            float u = 0.f;
            #pragma unroll
            for (int d2 = 0; d2 < 16; d2++) u += sS[q * 16 + d2] * W1[q * 16 + d2][c];
            red[q][c] = u;
        }
        __syncthreads();
        if (t < DD) suS[t] = red[0][t] + red[1][t] + red[2][t] + red[3][t] + (float)NN * bvS[t];
        __syncthreads();

        // ---- H: weff = Wb + C0*(A@T' + qk su^T) -> B3 ; beff ----
        {
            float acc[4][4];
            #pragma unroll
            for (int a = 0; a < 4; a++)
                #pragma unroll
                for (int b = 0; b < 4; b++) acc[a][b] = qkS[r0 + a] * suS[c0 + b];
            #pragma unroll 2
            for (int e = 0; e < DD; e += 4)
                mm4x4(acc,
                      *(const float4*)&W2[r0 + 0][e], *(const float4*)&W2[r0 + 1][e],
                      *(const float4*)&W2[r0 + 2][e], *(const float4*)&W2[r0 + 3][e],
                      *(const float4*)&W5[e + 0][c0], *(const float4*)&W5[e + 1][c0],
                      *(const float4*)&W5[e + 2][c0], *(const float4*)&W5[e + 3][c0]);
            float wloc[4][4];
            #pragma unroll
            for (int a = 0; a < 4; a++)
                #pragma unroll
                for (int b = 0; b < 4; b++)
                    wloc[a][b] = W4[r0 + a][c0 + b] + C0F * acc[a][b];
            {   // beff partials (reads W5 only)
                const int c = t & 63, q = t >> 6;
                float u = 0.f;
                #pragma unroll
                for (int e2 = 0; e2 < 16; e2++) u += kqS[q * 16 + e2] * W5[q * 16 + e2][c];
                red[q][c] = u;
            }
            __syncthreads();            // red visible; B3 (G) reads done
            #pragma unroll
            for (int a = 0; a < 4; a++)
                *(float4*)&B3[r0 + a][c0] = make_float4(wloc[a][0], wloc[a][1], wloc[a][2], wloc[a][3]);
            if (t < DD) beS[t] = Acc<T>::ld(blkb, bOff + t)
                               + C0F * (red[0][t] + red[1][t] + red[2][t] + red[3][t]
                                        + qbkS[0] * suS[t]);
        }
        __syncthreads();

        // ---- apply: h' = gelu(h@weff + beff) on resident rows ----
        float o[2][4];
        #pragma unroll
        for (int a = 0; a < 2; a++) {
            const int row = r + 16 * a;
            float acc2[4];
            #pragma unroll
            for (int b = 0; b < 4; b++) acc2[b] = beS[c4 + b];
            for (int d = 0; d < DD; d++) {
                float hv = sH[row][d];
                float4 w4 = *(const float4*)&B3[d][c4];
                acc2[0] += hv * w4.x; acc2[1] += hv * w4.y;
                acc2[2] += hv * w4.z; acc2[3] += hv * w4.w;
            }
            #pragma unroll
            for (int b = 0; b < 4; b++) o[a][b] = gelu_exact(acc2[b]);
        }

        if (layer == NLAYER - 1) {
            float pbv = Acc<T>::ld(pb, 0);
            #pragma unroll
            for (int a = 0; a < 2; a++) {
                float p = 0.f;
                #pragma unroll
                for (int b = 0; b < 4; b++) p += o[a][b] * Acc<T>::ld(pw, c4 + b);
                p += __shfl_xor(p, 1);
                p += __shfl_xor(p, 2);
                p += __shfl_xor(p, 4);
                p += __shfl_xor(p, 8);
                if ((t & 15) == 0) Acc<T>::st(out, row0 + r + 16 * a, p + pbv);
            }
        } else {
            __syncthreads();    // weff/beS/sH reads done before sH overwrite
            #pragma unroll
            for (int a = 0; a < 2; a++)
                *(float4*)&sH[r + 16 * a][c4] =
                    make_float4(o[a][0], o[a][1], o[a][2], o[a][3]);
            __syncthreads();
        }
    }
}

__global__ __launch_bounds__(NT, 1) void gno_kernel(
    const void* x, const void* lw, const void* lb,
    const void* blkw, const void* blkb,
    const void* qw, const void* qb, const void* kw, const void* kb,
    const void* vw, const void* vb, const void* pw, const void* pb,
    void* out, float* Gpart, float* Gg, unsigned* bar, int mode)
{
    __shared__ alignas(16) float smem[SM_TOT];   // 94976 B
    __shared__ int stot;

    const int blk = blockIdx.x, t = threadIdx.x;

    bool isbf;
    if (mode >= 0) {
        isbf = (mode == 1);
    } else {
        // fallback: device dtype scan (same result in every block)
        if (t == 0) stot = 0;
        __syncthreads();
        int cdt = 0;
        const unsigned int* xw = (const unsigned int*)x;
        for (int i = t; i < 8192; i += NT) {
            unsigned u = xw[i] & 0xFFFFu;
            int e = (u >> 7) & 0xFF;
            cdt += (u == 0u || (e >= 100 && e <= 142)) ? 1 : 0;
        }
        atomicAdd(&stot, cdt);
        __syncthreads();
        isbf = (stot > 4915);
    }

    unsigned* aflag = bar;          // [256] producer epochs
    unsigned* cflag = bar + 256;    // [256] combine epochs

    if (isbf)
        run_net<bf16>(x, lw, lb, blkw, blkb, qw, qb, kw, kb, vw, vb, pw, pb,
                      out, Gpart, Gg, aflag, cflag, smem, blk, t);
    else
        run_net<float>(x, lw, lb, blkw, blkb, qw, qb, kw, kb, vw, vb, pw, pb,
                       out, Gpart, Gg, aflag, cflag, smem, blk, t);
}

extern "C" void kernel_launch(void* const* d_in, const int* in_sizes, int n_in,
                              void* d_out, int out_size, void* d_ws, size_t ws_size,
                              hipStream_t stream)
{
    const void* x    = d_in[0];
    const void* lw   = d_in[1];
    const void* lb   = d_in[2];
    const void* blkw = d_in[3];
    const void* blkb = d_in[4];
    const void* qw   = d_in[5];
    const void* qb   = d_in[6];
    const void* kw   = d_in[7];
    const void* kb   = d_in[8];
    const void* vw   = d_in[9];
    const void* vb   = d_in[10];
    const void* pw   = d_in[11];
    const void* pb   = d_in[12];

    // x = [2,64,64,3]: fp32 -> 98304 B, bf16 -> 49152 B
    int mode = -1;
    if (in_sizes && n_in > 0) {
        if (in_sizes[0] == 49152) mode = 1;
        else if (in_sizes[0] == 98304) mode = 0;
    }

    unsigned* bar = (unsigned*)d_ws;                      // [512] flag words
    float* Gpart  = (float*)d_ws + 512;                   // [256][2304] 2.36 MB
    float* Gg     = Gpart + (size_t)NBLK * PSZ;           // [4][2][2304] per-layer

    hipMemsetAsync(bar, 0, 512 * sizeof(unsigned), stream);
    gno_kernel<<<NBLK, NT, 0, stream>>>(x, lw, lb, blkw, blkb, qw, qb, kw, kb,
                                        vw, vb, pw, pb, d_out, Gpart, Gg, bar, mode);
}